// Round 1
// baseline (966.328 us; speedup 1.0000x reference)
//
#include <hip/hip_runtime.h>
#include <hip/hip_bf16.h>

#define B_   4
#define CIN_ 64
#define H_   128
#define W_   128
#define COUT_ 64
#define K_   3
#define KK_  9
#define OFFC_ 18   // 2*K*K
#define HW_  (H_*W_)

// ---------------------------------------------------------------------------
// Kernel 1: offset = conv2d(x, offset_w, offset_b), 3x3, stride 1, pad 1.
// grid: (HW/256, OFFC, B), block 256. One thread = one output pixel of one co.
// ---------------------------------------------------------------------------
__global__ __launch_bounds__(256) void offset_conv_kernel(
    const float* __restrict__ x,      // (B, CIN, H, W)
    const float* __restrict__ w,      // (OFFC, CIN, 3, 3)
    const float* __restrict__ bias,   // (OFFC,)
    float* __restrict__ offs)         // (B, OFFC, H, W)
{
    const int tid = threadIdx.x;
    const int co  = blockIdx.y;
    const int b   = blockIdx.z;
    const int pix = blockIdx.x * 256 + tid;
    const int ho  = pix >> 7;          // /W_
    const int wo  = pix & (W_ - 1);

    __shared__ float wls[CIN_ * KK_];  // 576 floats, this co's slice
    for (int i = tid; i < CIN_ * KK_; i += 256)
        wls[i] = w[co * CIN_ * KK_ + i];
    __syncthreads();

    float acc = bias[co];
    const float* xb = x + (size_t)b * CIN_ * HW_;
    #pragma unroll 4
    for (int c = 0; c < CIN_; ++c) {
        const float* plane = xb + c * HW_;
        const float* wr = &wls[c * KK_];
        #pragma unroll
        for (int ky = 0; ky < 3; ++ky) {
            const int y = ho + ky - 1;
            if (y < 0 || y >= H_) continue;
            const float* row = plane + y * W_;
            #pragma unroll
            for (int kx = 0; kx < 3; ++kx) {
                const int xc = wo + kx - 1;
                if (xc < 0 || xc >= W_) continue;
                acc = fmaf(row[xc], wr[ky * 3 + kx], acc);
            }
        }
    }
    offs[((size_t)b * OFFC_ + co) * HW_ + pix] = acc;
}

// ---------------------------------------------------------------------------
// Kernel 2: deformable conv. One thread = one output pixel, all 64 out chans.
// grid: (HW/256, B), block 256. Per k, stage w[:, :, k] (64x64 = 16 KB) in LDS.
// ---------------------------------------------------------------------------
__global__ __launch_bounds__(256) void deform_conv_kernel(
    const float* __restrict__ x,      // (B, CIN, H, W)
    const float* __restrict__ offs,   // (B, OFFC, H, W)
    const float* __restrict__ w,      // (COUT, CIN, 3, 3)
    const float* __restrict__ bias,   // (COUT,)
    float* __restrict__ out)          // (B, COUT, H, W)
{
    const int tid = threadIdx.x;
    const int b   = blockIdx.y;
    const int pix = blockIdx.x * 256 + tid;
    const int ho  = pix >> 7;
    const int wo  = pix & (W_ - 1);

    __shared__ float wls[COUT_ * CIN_];  // 16 KB: w[o][c][k] for fixed k

    float acc[COUT_];
    #pragma unroll
    for (int o = 0; o < COUT_; ++o) acc[o] = 0.0f;

    const float* xb   = x    + (size_t)b * CIN_ * HW_;
    const float* offb = offs + (size_t)b * OFFC_ * HW_;

    for (int k = 0; k < KK_; ++k) {
        // stage weight k-slice: wls[o*64+c] = w[(o*64+c)*9 + k]
        for (int i = tid; i < COUT_ * CIN_; i += 256)
            wls[i] = w[i * KK_ + k];
        __syncthreads();

        const int ky = k / 3, kx = k % 3;
        const float dy = offb[(2 * k + 0) * HW_ + pix];
        const float dx = offb[(2 * k + 1) * HW_ + pix];
        const float ys = (float)(ho - 1 + ky) + dy;
        const float xs = (float)(wo - 1 + kx) + dx;
        const float y0f = floorf(ys);
        const float x0f = floorf(xs);
        const float ly = ys - y0f;
        const float lx = xs - x0f;
        const int y0 = (int)y0f;
        const int x0 = (int)x0f;
        const int y1 = y0 + 1;
        const int x1 = x0 + 1;

        const bool y0v = (y0 >= 0) & (y0 < H_);
        const bool y1v = (y1 >= 0) & (y1 < H_);
        const bool x0v = (x0 >= 0) & (x0 < W_);
        const bool x1v = (x1 >= 0) & (x1 < W_);

        // per-corner masked bilinear weights (ref masks each corner separately)
        const float m00 = (y0v & x0v) ? (1.0f - ly) * (1.0f - lx) : 0.0f;
        const float m01 = (y0v & x1v) ? (1.0f - ly) * lx          : 0.0f;
        const float m10 = (y1v & x0v) ? ly * (1.0f - lx)          : 0.0f;
        const float m11 = (y1v & x1v) ? ly * lx                   : 0.0f;

        const int y0c = min(max(y0, 0), H_ - 1);
        const int y1c = min(max(y1, 0), H_ - 1);
        const int x0c = min(max(x0, 0), W_ - 1);
        const int x1c = min(max(x1, 0), W_ - 1);
        const int i00 = y0c * W_ + x0c;
        const int i01 = y0c * W_ + x1c;
        const int i10 = y1c * W_ + x0c;
        const int i11 = y1c * W_ + x1c;

        for (int c = 0; c < CIN_; ++c) {
            const float* plane = xb + c * HW_;
            const float s = m00 * plane[i00] + m01 * plane[i01]
                          + m10 * plane[i10] + m11 * plane[i11];
            const float* wr = &wls[c];   // wls[o*64 + c], stride 64 over o
            #pragma unroll
            for (int o = 0; o < COUT_; ++o)
                acc[o] = fmaf(s, wr[o * CIN_], acc[o]);
        }
        __syncthreads();
    }

    float* ob = out + (size_t)b * COUT_ * HW_;
    #pragma unroll
    for (int o = 0; o < COUT_; ++o)
        ob[o * HW_ + pix] = acc[o] + bias[o];
}

extern "C" void kernel_launch(void* const* d_in, const int* in_sizes, int n_in,
                              void* d_out, int out_size, void* d_ws, size_t ws_size,
                              hipStream_t stream) {
    const float* x        = (const float*)d_in[0];
    const float* offset_w = (const float*)d_in[1];
    const float* offset_b = (const float*)d_in[2];
    const float* deform_w = (const float*)d_in[3];
    const float* deform_b = (const float*)d_in[4];
    float* out = (float*)d_out;
    float* offs = (float*)d_ws;  // (B, OFFC, H, W) = 4.72 MB

    dim3 g1(HW_ / 256, OFFC_, B_);
    offset_conv_kernel<<<g1, 256, 0, stream>>>(x, offset_w, offset_b, offs);

    dim3 g2(HW_ / 256, B_);
    deform_conv_kernel<<<g2, 256, 0, stream>>>(x, offs, deform_w, deform_b, out);
}

// Round 2
// 259.241 us; speedup vs baseline: 3.7275x; 3.7275x over previous
//
#include <hip/hip_runtime.h>

#define B_    4
#define CIN_  64
#define H_    128
#define W_    128
#define COUT_ 64
#define KK_   9
#define OFFC_ 18
#define HW_   (H_*W_)
#define TILE_ 64

typedef float float4v __attribute__((ext_vector_type(4)));

// One fused kernel. Block = 256 threads = 64 pixels (one half-row).
// Phase A: offset conv (18 ch) -> offs_lds.  Phase B: deformable conv GEMM.
__global__ __launch_bounds__(256, 4) void fused_deform_kernel(
    const float* __restrict__ x,    // (B, 64, 128, 128)
    const float* __restrict__ ow,   // (18, 64, 3, 3)
    const float* __restrict__ obias,// (18,)
    const float* __restrict__ dw,   // (64, 64, 3, 3)
    const float* __restrict__ dbias,// (64,)
    float* __restrict__ out)        // (B, 64, 128, 128)
{
    __shared__ float smp[CIN_ * TILE_];      // [c][p] samples       16 KB
    __shared__ float wk [CIN_ * COUT_];      // [c][o] weight slice  16 KB (aliased owk in phase A)
    __shared__ float offs_lds[OFFC_ * TILE_];// [co][p] offsets      4.5 KB

    const int tid = threadIdx.x;
    const int b   = blockIdx.y;
    const int pixbase = blockIdx.x * TILE_;
    const int ho    = pixbase >> 7;          // row (all pixels in block share it)
    const int wbase = pixbase & (W_ - 1);
    const int p  = tid & 63;                 // my pixel (phases A + staging)
    const int g  = tid >> 6;                 // my wave/group 0..3
    const int wo = wbase + p;

    const float* xb = x + (size_t)b * CIN_ * HW_;

    // ---------------- Phase A: offset conv, co = g + 4*j ----------------
    float* owk = wk;                         // [c*20 + co], co padded to 20
    // zero the pad slots once (read by j=4 for g>=2, result never stored)
    for (int c = tid; c < CIN_; c += 256) { owk[c*20 + 18] = 0.f; owk[c*20 + 19] = 0.f; }

    float oacc[5] = {0.f, 0.f, 0.f, 0.f, 0.f};
    for (int k = 0; k < KK_; ++k) {
        __syncthreads();                     // protect owk from previous iter's readers
        for (int idx = tid; idx < OFFC_ * CIN_; idx += 256) {
            const int co = idx >> 6, c = idx & 63;
            owk[c*20 + co] = ow[(co * CIN_ + c) * KK_ + k];
        }
        __syncthreads();
        const int ky = k / 3, kx = k % 3;
        const int y    = ho + ky - 1;
        const int xcol = wo + kx - 1;
        const bool xv  = (xcol >= 0) & (xcol < W_);
        if (y >= 0 && y < H_) {
            const float* rowc = xb + y * W_;
            for (int c = 0; c < CIN_; ++c) {
                const float v = xv ? rowc[(size_t)c * HW_ + xcol] : 0.0f;
                #pragma unroll
                for (int j = 0; j < 5; ++j)
                    oacc[j] = fmaf(v, owk[c*20 + g + 4*j], oacc[j]);
            }
        }
    }
    __syncthreads();
    #pragma unroll
    for (int j = 0; j < 5; ++j) {
        const int co = g + 4*j;
        if (co < OFFC_) offs_lds[co * TILE_ + p] = oacc[j] + obias[co];
    }
    __syncthreads();

    // ---------------- Phase B: deformable conv ----------------
    const int p4 = (tid & 15) * 4;           // GEMM tile: 4 pixels
    const int o4 = (tid >> 4) * 4;           // GEMM tile: 4 out chans
    float4v acc[4];
    #pragma unroll
    for (int oi = 0; oi < 4; ++oi) acc[oi] = (float4v)0.f;

    for (int k = 0; k < KK_; ++k) {
        // stage weight slice wk[c*64+o] = dw[o][c][k]
        #pragma unroll
        for (int j = 0; j < 16; ++j) {
            const int idx = tid + 256 * j;
            const int c = idx >> 6, o = idx & 63;
            wk[idx] = dw[(o * CIN_ + c) * KK_ + k];
        }
        // bilinear coords for my pixel p
        const int ky = k / 3, kx = k % 3;
        const float dy = offs_lds[(2*k + 0) * TILE_ + p];
        const float dx = offs_lds[(2*k + 1) * TILE_ + p];
        const float ys = (float)(ho + ky - 1) + dy;
        const float xs = (float)(wo + kx - 1) + dx;
        const float y0f = floorf(ys), x0f = floorf(xs);
        const float ly = ys - y0f,   lx = xs - x0f;
        const int y0 = (int)y0f, x0 = (int)x0f;
        const int y1 = y0 + 1,   x1 = x0 + 1;
        const bool y0v = (y0 >= 0) & (y0 < H_);
        const bool y1v = (y1 >= 0) & (y1 < H_);
        const bool x0v = (x0 >= 0) & (x0 < W_);
        const bool x1v = (x1 >= 0) & (x1 < W_);
        const float m00 = (y0v & x0v) ? (1.f - ly) * (1.f - lx) : 0.f;
        const float m01 = (y0v & x1v) ? (1.f - ly) * lx         : 0.f;
        const float m10 = (y1v & x0v) ? ly * (1.f - lx)         : 0.f;
        const float m11 = (y1v & x1v) ? ly * lx                 : 0.f;
        const int y0c = min(max(y0, 0), H_ - 1);
        const int y1c = min(max(y1, 0), H_ - 1);
        const int x0c = min(max(x0, 0), W_ - 1);
        const int x1c = min(max(x1, 0), W_ - 1);
        const int i00 = y0c * W_ + x0c;
        const int i01 = y0c * W_ + x1c;
        const int i10 = y1c * W_ + x0c;
        const int i11 = y1c * W_ + x1c;

        // stage bilinear samples for my 16 channels
        #pragma unroll 4
        for (int j = 0; j < 16; ++j) {
            const int c = g * 16 + j;
            const float* plane = xb + (size_t)c * HW_;
            const float s = m00 * plane[i00] + m01 * plane[i01]
                          + m10 * plane[i10] + m11 * plane[i11];
            smp[c * TILE_ + p] = s;
        }
        __syncthreads();

        // register-tiled GEMM: 4 out-chans x 4 pixels per thread
        #pragma unroll 4
        for (int c = 0; c < CIN_; ++c) {
            const float4v sv = *(const float4v*)&smp[c * TILE_ + p4];
            const float4v wv = *(const float4v*)&wk [c * COUT_ + o4];
            #pragma unroll
            for (int oi = 0; oi < 4; ++oi)
                acc[oi] += wv[oi] * sv;
        }
        __syncthreads();                     // protect smp/wk before next stage
    }

    // epilogue
    float* obp = out + (size_t)b * COUT_ * HW_ + pixbase;
    #pragma unroll
    for (int oi = 0; oi < 4; ++oi) {
        const int o = o4 + oi;
        float4v r = acc[oi];
        const float bv = dbias[o];
        r += bv;
        *(float4v*)&obp[(size_t)o * HW_ + p4] = r;
    }
}

extern "C" void kernel_launch(void* const* d_in, const int* in_sizes, int n_in,
                              void* d_out, int out_size, void* d_ws, size_t ws_size,
                              hipStream_t stream) {
    const float* x        = (const float*)d_in[0];
    const float* offset_w = (const float*)d_in[1];
    const float* offset_b = (const float*)d_in[2];
    const float* deform_w = (const float*)d_in[3];
    const float* deform_b = (const float*)d_in[4];
    float* out = (float*)d_out;

    dim3 grid(HW_ / TILE_, B_);
    fused_deform_kernel<<<grid, 256, 0, stream>>>(x, offset_w, offset_b,
                                                  deform_w, deform_b, out);
}

// Round 3
// 123.571 us; speedup vs baseline: 7.8200x; 2.0979x over previous
//
#include <hip/hip_runtime.h>
#include <hip/hip_bf16.h>

#define B_    4
#define CIN_  64
#define H_    128
#define W_    128
#define COUT_ 64
#define KK_   9
#define OFFC_ 18
#define HW_   (H_*W_)
#define TILE_ 64

typedef short bf8  __attribute__((ext_vector_type(8)));   // 8 bf16 (4 VGPRs)
typedef float f32x4 __attribute__((ext_vector_type(4)));

__device__ inline short f2bf(float f) {
    __hip_bfloat16 h = __float2bfloat16(f);
    union { __hip_bfloat16 h; short s; } u; u.h = h; return u.s;
}

// ---------------------------------------------------------------------------
// Prep: repack weights to bf16, MFMA-friendly layout.
//   dwbf[k][o][c]  (9*64*64)   owbf[k][co<32][c] (9*32*64, rows 18..31 = 0)
// ---------------------------------------------------------------------------
__global__ __launch_bounds__(256) void prep_weights(
    const float* __restrict__ ow, const float* __restrict__ dw,
    short* __restrict__ dwbf, short* __restrict__ owbf)
{
    const int idx = blockIdx.x * 256 + threadIdx.x;
    if (idx < KK_ * COUT_ * CIN_) {
        const int k = idx / (COUT_ * CIN_);
        const int r = idx % (COUT_ * CIN_);
        const int o = r >> 6, c = r & 63;
        dwbf[idx] = f2bf(dw[(o * CIN_ + c) * KK_ + k]);
    }
    if (idx < KK_ * 32 * CIN_) {
        const int k = idx / (32 * CIN_);
        const int r = idx % (32 * CIN_);
        const int co = r >> 6, c = r & 63;
        owbf[idx] = f2bf(co < OFFC_ ? ow[(co * CIN_ + c) * KK_ + k] : 0.0f);
    }
}

// ---------------------------------------------------------------------------
// Fused kernel. Block = 256 thr (4 waves) = 64 pixels (half row), grid (256,4).
// LDS B-operand layout [row][c] bf16, rows 128 B, chunk-XOR swizzle:
//   elem(row, c) = row*64 + (((c>>3) ^ (row&7)) << 3) + (c&7)
// ---------------------------------------------------------------------------
__global__ __launch_bounds__(256, 5) void fused_deform_mfma(
    const float* __restrict__ x,     // (B,64,128,128) f32
    const short* __restrict__ owbf,  // [9][32][64] bf16
    const float* __restrict__ obias, // (18,)
    const short* __restrict__ dwbf,  // [9][64][64] bf16
    const float* __restrict__ dbias, // (64,)
    float* __restrict__ out)         // (B,64,128,128) f32
{
    __shared__ union {
        short xt[3 * 66 * 64];       // phase A: [y][q][c], q = col+1 (25.3 KB)
        short smp[2 * 64 * 64];      // phase B: [buf][p][c]           (16 KB)
    } u;
    __shared__ float offs[OFFC_ * TILE_];

    const int tid = threadIdx.x;
    const int b   = blockIdx.y;
    const int pixbase = blockIdx.x * TILE_;
    const int ho    = pixbase >> 7;
    const int wbase = pixbase & (W_ - 1);
    const int lane  = tid & 63;
    const int wv    = tid >> 6;              // wave 0..3
    const int arow  = lane & 15;             // MFMA frag row/col index
    const int kseg  = lane >> 4;             // 0..3

    const float* xb = x + (size_t)b * CIN_ * HW_;

    // ---- stage x patch (3 rows x 66 cols x 64 ch) once, bf16 swizzled ----
    for (int base = 0; base < 3 * 66 * 8; base += 256) {
        const int idx = base + tid;
        if (idx < 3 * 66 * 8) {
            const int cc = idx & 7;          // c-chunk
            const int qy = idx >> 3;         // 0..197
            const int y  = qy / 66;
            const int q  = qy - y * 66;
            const int gy = ho + y - 1;
            const int gx = wbase + q - 1;
            bf8 v;
            if (gy >= 0 && gy < H_ && gx >= 0 && gx < W_) {
                const float* p0 = xb + (size_t)(cc * 8) * HW_ + gy * W_ + gx;
                #pragma unroll
                for (int j = 0; j < 8; ++j) v[j] = f2bf(p0[(size_t)j * HW_]);
            } else {
                #pragma unroll
                for (int j = 0; j < 8; ++j) v[j] = 0;
            }
            *(bf8*)&u.xt[(y * 66 + q) * 64 + ((cc ^ (q & 7)) << 3)] = v;
        }
    }
    __syncthreads();

    // ---- Phase A: offset conv via MFMA ----
    // wave wv: co-tile m = wv&1 (co base m*16), pixel half h = wv>>1
    {
        const int m = wv & 1;
        const int h = wv >> 1;
        f32x4 acca[2];
        acca[0] = (f32x4)0.f; acca[1] = (f32x4)0.f;
        for (int t = 0; t < KK_; ++t) {
            const int ky = t / 3, kx = t % 3;
            #pragma unroll
            for (int kc = 0; kc < 2; ++kc) {
                const int cbase = kc * 32 + kseg * 8;
                const bf8 afrag = *(const bf8*)&owbf[(t * 32 + m * 16 + arow) * 64 + cbase];
                const int cchunk = cbase >> 3;
                #pragma unroll
                for (int nt = 0; nt < 2; ++nt) {
                    const int p = h * 32 + nt * 16 + arow;
                    const int q = p + kx;
                    const bf8 bfrag = *(const bf8*)&u.xt[(ky * 66 + q) * 64 + ((cchunk ^ (q & 7)) << 3)];
                    acca[nt] = __builtin_amdgcn_mfma_f32_16x16x32_bf16(afrag, bfrag, acca[nt], 0, 0, 0);
                }
            }
        }
        #pragma unroll
        for (int nt = 0; nt < 2; ++nt) {
            #pragma unroll
            for (int r = 0; r < 4; ++r) {
                const int co = m * 16 + kseg * 4 + r;
                if (co < OFFC_) {
                    const int p = h * 32 + nt * 16 + arow;
                    offs[co * TILE_ + p] = acca[nt][r] + obias[co];
                }
            }
        }
    }
    __syncthreads();   // offs ready; xt dead -> smp may reuse the union

    // ---- Phase B: deformable conv ----
    const int p  = lane;                     // staging pixel
    const int wo = wbase + p;

    auto stageB = [&](int t, int dstbuf) {
        const int ky = t / 3, kx = t % 3;
        const float dy = offs[(2 * t + 0) * TILE_ + p];
        const float dx = offs[(2 * t + 1) * TILE_ + p];
        const float ys = (float)(ho + ky - 1) + dy;
        const float xs = (float)(wo + kx - 1) + dx;
        const float y0f = floorf(ys), x0f = floorf(xs);
        const float ly = ys - y0f, lx = xs - x0f;
        const int y0 = (int)y0f, x0 = (int)x0f;
        const int y1 = y0 + 1,   x1 = x0 + 1;
        const bool y0v = (y0 >= 0) & (y0 < H_);
        const bool y1v = (y1 >= 0) & (y1 < H_);
        const bool x0v = (x0 >= 0) & (x0 < W_);
        const bool x1v = (x1 >= 0) & (x1 < W_);
        const float m00 = (y0v & x0v) ? (1.f - ly) * (1.f - lx) : 0.f;
        const float m01 = (y0v & x1v) ? (1.f - ly) * lx         : 0.f;
        const float m10 = (y1v & x0v) ? ly * (1.f - lx)         : 0.f;
        const float m11 = (y1v & x1v) ? ly * lx                 : 0.f;
        const int y0c = min(max(y0, 0), H_ - 1);
        const int y1c = min(max(y1, 0), H_ - 1);
        const int x0c = min(max(x0, 0), W_ - 1);
        const int x1c = min(max(x1, 0), W_ - 1);
        const int i00 = y0c * W_ + x0c;
        const int i01 = y0c * W_ + x1c;
        const int i10 = y1c * W_ + x0c;
        const int i11 = y1c * W_ + x1c;
        #pragma unroll
        for (int cc2 = 0; cc2 < 2; ++cc2) {
            const int chunk = wv * 2 + cc2;
            const float* pl = xb + (size_t)(chunk * 8) * HW_;
            bf8 v;
            #pragma unroll
            for (int j = 0; j < 8; ++j) {
                const float* plane = pl + (size_t)j * HW_;
                const float s = m00 * plane[i00] + m01 * plane[i01]
                              + m10 * plane[i10] + m11 * plane[i11];
                v[j] = f2bf(s);
            }
            *(bf8*)&u.smp[dstbuf * 4096 + p * 64 + ((chunk ^ (p & 7)) << 3)] = v;
        }
    };

    f32x4 accb[4];
    #pragma unroll
    for (int nt = 0; nt < 4; ++nt) accb[nt] = (f32x4)0.f;

    int buf = 0;
    stageB(0, 0);
    __syncthreads();
    for (int t = 0; t < KK_; ++t) {
        if (t < KK_ - 1) stageB(t + 1, buf ^ 1);
        #pragma unroll
        for (int kc = 0; kc < 2; ++kc) {
            const int cbase = kc * 32 + kseg * 8;
            const bf8 afrag = *(const bf8*)&dwbf[(t * 64 + wv * 16 + arow) * 64 + cbase];
            const int cchunk = cbase >> 3;
            #pragma unroll
            for (int nt = 0; nt < 4; ++nt) {
                const int pp = nt * 16 + arow;
                const bf8 bfrag = *(const bf8*)&u.smp[buf * 4096 + pp * 64 + ((cchunk ^ (pp & 7)) << 3)];
                accb[nt] = __builtin_amdgcn_mfma_f32_16x16x32_bf16(afrag, bfrag, accb[nt], 0, 0, 0);
            }
        }
        __syncthreads();
        buf ^= 1;
    }

    // ---- epilogue: out[b][o][pixbase + pp], o = wv*16 + kseg*4 + r ----
    float* ob = out + (size_t)b * COUT_ * HW_ + pixbase;
    #pragma unroll
    for (int nt = 0; nt < 4; ++nt) {
        const int pp = nt * 16 + arow;
        #pragma unroll
        for (int r = 0; r < 4; ++r) {
            const int o = wv * 16 + kseg * 4 + r;
            ob[(size_t)o * HW_ + pp] = accb[nt][r] + dbias[o];
        }
    }
}

extern "C" void kernel_launch(void* const* d_in, const int* in_sizes, int n_in,
                              void* d_out, int out_size, void* d_ws, size_t ws_size,
                              hipStream_t stream) {
    const float* x        = (const float*)d_in[0];
    const float* offset_w = (const float*)d_in[1];
    const float* offset_b = (const float*)d_in[2];
    const float* deform_w = (const float*)d_in[3];
    const float* deform_b = (const float*)d_in[4];
    float* out = (float*)d_out;

    short* dwbf = (short*)d_ws;                       // 9*64*64 bf16 = 73728 B
    short* owbf = (short*)((char*)d_ws + 73728);      // 9*32*64 bf16 = 36864 B

    prep_weights<<<144, 256, 0, stream>>>(offset_w, deform_w, dwbf, owbf);

    dim3 grid(HW_ / TILE_, B_);
    fused_deform_mfma<<<grid, 256, 0, stream>>>(x, owbf, offset_b, dwbf, deform_b, out);
}

// Round 4
// 74.312 us; speedup vs baseline: 13.0036x; 1.6629x over previous
//
#include <hip/hip_runtime.h>
#include <hip/hip_bf16.h>

#define B_    4
#define CIN_  64
#define H_    128
#define W_    128
#define COUT_ 64
#define KK_   9
#define OFFC_ 18
#define HW_   (H_*W_)
#define TILE_ 64

typedef short bf8  __attribute__((ext_vector_type(8)));   // 8 bf16 (4 VGPRs)
typedef float f32x4 __attribute__((ext_vector_type(4)));

__device__ inline short f2bf(float f) {
    union { __hip_bfloat16 h; short s; } u; u.h = __float2bfloat16(f); return u.s;
}
__device__ inline float bf2f(short s) {
    union { unsigned u; float f; } v; v.u = ((unsigned)(unsigned short)s) << 16; return v.f;
}

// ---------------------------------------------------------------------------
// Prep 1: repack weights to bf16. dwbf[k][o][c], owbf[k][co<32][c] (pad rows 0)
// ---------------------------------------------------------------------------
__global__ __launch_bounds__(256) void prep_weights(
    const float* __restrict__ ow, const float* __restrict__ dw,
    short* __restrict__ dwbf, short* __restrict__ owbf)
{
    const int idx = blockIdx.x * 256 + threadIdx.x;
    if (idx < KK_ * COUT_ * CIN_) {
        const int k = idx / (COUT_ * CIN_);
        const int r = idx % (COUT_ * CIN_);
        const int o = r >> 6, c = r & 63;
        dwbf[idx] = f2bf(dw[(o * CIN_ + c) * KK_ + k]);
    }
    if (idx < KK_ * 32 * CIN_) {
        const int k = idx / (32 * CIN_);
        const int r = idx % (32 * CIN_);
        const int co = r >> 6, c = r & 63;
        owbf[idx] = f2bf(co < OFFC_ ? ow[(co * CIN_ + c) * KK_ + k] : 0.0f);
    }
}

// ---------------------------------------------------------------------------
// Prep 2: transpose x (B,C,H,W) f32 -> xt (B,H*W,C) bf16 (channels-last).
// Block 256 = 64 pixels x 4 channel-groups; reads coalesced per wave.
// ---------------------------------------------------------------------------
__global__ __launch_bounds__(256) void transpose_x(
    const float* __restrict__ x, short* __restrict__ xt)
{
    const int tid = threadIdx.x;
    const int p   = tid & 63;
    const int g   = tid >> 6;            // channel group 0..3 (16 ch each)
    const int pix = blockIdx.x * 64 + p;
    const int b   = blockIdx.y;

    const float* src = x + ((size_t)b * CIN_ + g * 16) * HW_ + pix;
    short vals[16];
    #pragma unroll
    for (int j = 0; j < 16; ++j) vals[j] = f2bf(src[(size_t)j * HW_]);
    short* dst = xt + ((size_t)b * HW_ + pix) * 64 + g * 16;
    *(bf8*)dst       = *(bf8*)&vals[0];
    *(bf8*)(dst + 8) = *(bf8*)&vals[8];
}

// ---------------------------------------------------------------------------
// Fused kernel. Block = 256 thr (4 waves) = 64 pixels (half row), grid (256,4).
// LDS B-operand layout [row][c] bf16, rows 128 B, chunk-XOR swizzle:
//   elem(row, c) = row*64 + (((c>>3) ^ (row&7)) << 3) + (c&7)
// ---------------------------------------------------------------------------
__global__ __launch_bounds__(256, 5) void fused_deform_mfma(
    const short* __restrict__ xt,    // (B,HW,64) bf16 channels-last
    const short* __restrict__ owbf,  // [9][32][64] bf16
    const float* __restrict__ obias, // (18,)
    const short* __restrict__ dwbf,  // [9][64][64] bf16
    const float* __restrict__ dbias, // (64,)
    float* __restrict__ out)         // (B,64,128,128) f32
{
    __shared__ union {
        short xt[3 * 66 * 64];       // phase A: [y][q][c], q = col+1 (25.3 KB)
        short smp[2 * 64 * 64];      // phase B: [buf][p][c]           (16 KB)
    } u;
    __shared__ float offs[OFFC_ * TILE_];

    const int tid = threadIdx.x;
    const int b   = blockIdx.y;
    const int pixbase = blockIdx.x * TILE_;
    const int ho    = pixbase >> 7;
    const int wbase = pixbase & (W_ - 1);
    const int lane  = tid & 63;
    const int wv    = tid >> 6;              // wave 0..3
    const int arow  = lane & 15;             // MFMA frag row/col index
    const int kseg  = lane >> 4;             // 0..3

    const short* xbt = xt + (size_t)b * HW_ * 64;

    // ---- stage x patch (3 rows x 66 cols x 64 ch) once, swizzled ----
    for (int base = 0; base < 3 * 66 * 8; base += 256) {
        const int idx = base + tid;
        if (idx < 3 * 66 * 8) {
            const int cc = idx & 7;          // c-chunk
            const int qy = idx >> 3;         // 0..197
            const int y  = qy / 66;
            const int q  = qy - y * 66;
            const int gy = ho + y - 1;
            const int gx = wbase + q - 1;
            bf8 v;
            if (gy >= 0 && gy < H_ && gx >= 0 && gx < W_) {
                v = *(const bf8*)&xbt[(size_t)(gy * W_ + gx) * 64 + cc * 8];
            } else {
                #pragma unroll
                for (int j = 0; j < 8; ++j) v[j] = 0;
            }
            *(bf8*)&u.xt[(y * 66 + q) * 64 + ((cc ^ (q & 7)) << 3)] = v;
        }
    }
    __syncthreads();

    // ---- Phase A: offset conv via MFMA ----
    {
        const int m = wv & 1;                // co tile
        const int h = wv >> 1;               // pixel half
        f32x4 acca[2];
        acca[0] = (f32x4)0.f; acca[1] = (f32x4)0.f;
        for (int t = 0; t < KK_; ++t) {
            const int ky = t / 3, kx = t % 3;
            #pragma unroll
            for (int kc = 0; kc < 2; ++kc) {
                const int cbase = kc * 32 + kseg * 8;
                const bf8 afrag = *(const bf8*)&owbf[(t * 32 + m * 16 + arow) * 64 + cbase];
                const int cchunk = cbase >> 3;
                #pragma unroll
                for (int nt = 0; nt < 2; ++nt) {
                    const int pp = h * 32 + nt * 16 + arow;
                    const int q = pp + kx;
                    const bf8 bfrag = *(const bf8*)&u.xt[(ky * 66 + q) * 64 + ((cchunk ^ (q & 7)) << 3)];
                    acca[nt] = __builtin_amdgcn_mfma_f32_16x16x32_bf16(afrag, bfrag, acca[nt], 0, 0, 0);
                }
            }
        }
        #pragma unroll
        for (int nt = 0; nt < 2; ++nt) {
            #pragma unroll
            for (int r = 0; r < 4; ++r) {
                const int co = m * 16 + kseg * 4 + r;
                if (co < OFFC_) {
                    const int pp = h * 32 + nt * 16 + arow;
                    offs[co * TILE_ + pp] = acca[nt][r] + obias[co];
                }
            }
        }
    }
    __syncthreads();   // offs ready; xt LDS dead -> smp may reuse the union

    // ---- Phase B: deformable conv ----
    const int p  = lane;                     // staging pixel
    const int wo = wbase + p;

    auto stageB = [&](int t, int dstbuf) {
        const int ky = t / 3, kx = t % 3;
        const float dy = offs[(2 * t + 0) * TILE_ + p];
        const float dx = offs[(2 * t + 1) * TILE_ + p];
        const float ys = (float)(ho + ky - 1) + dy;
        const float xs = (float)(wo + kx - 1) + dx;
        const float y0f = floorf(ys), x0f = floorf(xs);
        const float ly = ys - y0f, lx = xs - x0f;
        const int y0 = (int)y0f, x0 = (int)x0f;
        const int y1 = y0 + 1,   x1 = x0 + 1;
        const bool y0v = (y0 >= 0) & (y0 < H_);
        const bool y1v = (y1 >= 0) & (y1 < H_);
        const bool x0v = (x0 >= 0) & (x0 < W_);
        const bool x1v = (x1 >= 0) & (x1 < W_);
        const float m00 = (y0v & x0v) ? (1.f - ly) * (1.f - lx) : 0.f;
        const float m01 = (y0v & x1v) ? (1.f - ly) * lx         : 0.f;
        const float m10 = (y1v & x0v) ? ly * (1.f - lx)         : 0.f;
        const float m11 = (y1v & x1v) ? ly * lx                 : 0.f;
        const int y0c = min(max(y0, 0), H_ - 1);
        const int y1c = min(max(y1, 0), H_ - 1);
        const int x0c = min(max(x0, 0), W_ - 1);
        const int x1c = min(max(x1, 0), W_ - 1);
        const short* c00 = xbt + (size_t)(y0c * W_ + x0c) * 64;
        const short* c01 = xbt + (size_t)(y0c * W_ + x1c) * 64;
        const short* c10 = xbt + (size_t)(y1c * W_ + x0c) * 64;
        const short* c11 = xbt + (size_t)(y1c * W_ + x1c) * 64;
        #pragma unroll
        for (int cc2 = 0; cc2 < 2; ++cc2) {
            const int chunk = wv * 2 + cc2;
            const int co8 = chunk * 8;
            const bf8 v00 = *(const bf8*)(c00 + co8);
            const bf8 v01 = *(const bf8*)(c01 + co8);
            const bf8 v10 = *(const bf8*)(c10 + co8);
            const bf8 v11 = *(const bf8*)(c11 + co8);
            bf8 v;
            #pragma unroll
            for (int j = 0; j < 8; ++j) {
                const float s = m00 * bf2f(v00[j]) + m01 * bf2f(v01[j])
                              + m10 * bf2f(v10[j]) + m11 * bf2f(v11[j]);
                v[j] = f2bf(s);
            }
            *(bf8*)&u.smp[dstbuf * 4096 + p * 64 + ((chunk ^ (p & 7)) << 3)] = v;
        }
    };

    f32x4 accb[4];
    #pragma unroll
    for (int nt = 0; nt < 4; ++nt) accb[nt] = (f32x4)0.f;

    int buf = 0;
    stageB(0, 0);
    __syncthreads();
    for (int t = 0; t < KK_; ++t) {
        if (t < KK_ - 1) stageB(t + 1, buf ^ 1);
        #pragma unroll
        for (int kc = 0; kc < 2; ++kc) {
            const int cbase = kc * 32 + kseg * 8;
            const bf8 afrag = *(const bf8*)&dwbf[(t * 64 + wv * 16 + arow) * 64 + cbase];
            const int cchunk = cbase >> 3;
            #pragma unroll
            for (int nt = 0; nt < 4; ++nt) {
                const int pp = nt * 16 + arow;
                const bf8 bfrag = *(const bf8*)&u.smp[buf * 4096 + pp * 64 + ((cchunk ^ (pp & 7)) << 3)];
                accb[nt] = __builtin_amdgcn_mfma_f32_16x16x32_bf16(afrag, bfrag, accb[nt], 0, 0, 0);
            }
        }
        __syncthreads();
        buf ^= 1;
    }

    // ---- epilogue ----
    float* ob = out + (size_t)b * COUT_ * HW_ + pixbase;
    #pragma unroll
    for (int nt = 0; nt < 4; ++nt) {
        const int pp = nt * 16 + arow;
        #pragma unroll
        for (int r = 0; r < 4; ++r) {
            const int o = wv * 16 + kseg * 4 + r;
            ob[(size_t)o * HW_ + pp] = accb[nt][r] + dbias[o];
        }
    }
}

extern "C" void kernel_launch(void* const* d_in, const int* in_sizes, int n_in,
                              void* d_out, int out_size, void* d_ws, size_t ws_size,
                              hipStream_t stream) {
    const float* x        = (const float*)d_in[0];
    const float* offset_w = (const float*)d_in[1];
    const float* offset_b = (const float*)d_in[2];
    const float* deform_w = (const float*)d_in[3];
    const float* deform_b = (const float*)d_in[4];
    float* out = (float*)d_out;

    short* dwbf = (short*)d_ws;                        // 73728 B
    short* owbf = (short*)((char*)d_ws + 73728);       // 36864 B
    short* xt   = (short*)((char*)d_ws + 110592);      // 8 MB channels-last bf16

    prep_weights<<<144, 256, 0, stream>>>(offset_w, deform_w, dwbf, owbf);
    dim3 gt(HW_ / 64, B_);
    transpose_x<<<gt, 256, 0, stream>>>(x, xt);

    dim3 grid(HW_ / TILE_, B_);
    fused_deform_mfma<<<grid, 256, 0, stream>>>(xt, owbf, offset_b, dwbf, deform_b, out);
}